// Round 6
// baseline (386.300 us; speedup 1.0000x reference)
//
#include <hip/hip_runtime.h>
#include <hip/hip_bf16.h>

#define T_SEQ 2048
#define D_MODEL 2048
#define NH 16
#define NKVH 4
#define HD 128

typedef __attribute__((ext_vector_type(8))) short bf16x8;
typedef __attribute__((ext_vector_type(4))) float f32x4;

static __device__ __forceinline__ short f32_to_bf16(float f) {
    unsigned u = __float_as_uint(f);
    u += 0x7fffu + ((u >> 16) & 1u);
    return (short)(u >> 16);
}
static __device__ __forceinline__ float bf16_to_f32(short s) {
    return __uint_as_float(((unsigned)(unsigned short)s) << 16);
}
static __device__ __forceinline__ void gl_to_lds16(const void* g, void* l) {
    __builtin_amdgcn_global_load_lds(
        (const __attribute__((address_space(1))) unsigned int*)g,
        (__attribute__((address_space(3))) unsigned int*)l, 16, 0, 0);
}

// ---------------------------------------------------------------------------
// Pipelined GEMM (R4): A bf16 (M x K), Bt bf16 (N x K), BK=64, BN=128,
// dbuf LDS, raw vmcnt(0)+s_barrier, prefetch-after-barrier, xor-swizzle.
// ---------------------------------------------------------------------------
template<int BM>
__global__ __launch_bounds__(256) void gemm_bt_kernel(
    const short* __restrict__ A, const short* __restrict__ Bt,
    float* __restrict__ Cf, short* __restrict__ Cb,
    int M, int N, int K, const float* __restrict__ bias, int act)
{
    constexpr int NI = (BM == 128) ? 4 : 2;
    constexpr int ACH = BM / 32;
    __shared__ short Alds[2][BM * 64];
    __shared__ short Blds[2][128 * 64];

    const int tid = threadIdx.x;
    const int wave = tid >> 6, lane = tid & 63;
    const int l16 = lane & 15, quad = lane >> 4;
    const int wm = (BM == 128) ? (wave >> 1) * 64 : 0;
    const int wn = (BM == 128) ? (wave & 1) * 64 : wave * 32;
    const int m0 = blockIdx.y * BM, n0 = blockIdx.x * 128;
    const int niter = K >> 6;

    f32x4 acc[4][NI] = {};

    #pragma unroll
    for (int p = 0; p < ACH; ++p) {
        int li = p * 256 + tid;
        int row = li >> 3, sc = li & 7;
        gl_to_lds16(A + (size_t)(m0 + row) * K + ((sc ^ (row & 7)) * 8),
                    &Alds[0][(size_t)(p * 256 + wave * 64) * 8]);
    }
    #pragma unroll
    for (int p = 0; p < 4; ++p) {
        int li = p * 256 + tid;
        int row = li >> 3, sc = li & 7;
        gl_to_lds16(Bt + (size_t)(n0 + row) * K + ((sc ^ (row & 7)) * 8),
                    &Blds[0][(size_t)(p * 256 + wave * 64) * 8]);
    }

    for (int t = 0; t < niter; ++t) {
        asm volatile("s_waitcnt vmcnt(0)\n\ts_barrier" ::: "memory");

        if (t + 1 < niter) {
            int k1 = (t + 1) << 6;
            int nb = (t + 1) & 1;
            #pragma unroll
            for (int p = 0; p < ACH; ++p) {
                int li = p * 256 + tid;
                int row = li >> 3, sc = li & 7;
                gl_to_lds16(A + (size_t)(m0 + row) * K + k1 + ((sc ^ (row & 7)) * 8),
                            &Alds[nb][(size_t)(p * 256 + wave * 64) * 8]);
            }
            #pragma unroll
            for (int p = 0; p < 4; ++p) {
                int li = p * 256 + tid;
                int row = li >> 3, sc = li & 7;
                gl_to_lds16(Bt + (size_t)(n0 + row) * K + k1 + ((sc ^ (row & 7)) * 8),
                            &Blds[nb][(size_t)(p * 256 + wave * 64) * 8]);
            }
        }

        const short* Ab = Alds[t & 1];
        const short* Bb = Blds[t & 1];
        #pragma unroll
        for (int kk = 0; kk < 2; ++kk) {
            bf16x8 a[4], b[NI];
            #pragma unroll
            for (int i = 0; i < 4; ++i)
                a[i] = *(const bf16x8*)
                    &Ab[(size_t)(wm + i * 16 + l16) * 64 + (((kk * 4 + quad) ^ (l16 & 7)) * 8)];
            #pragma unroll
            for (int i = 0; i < NI; ++i)
                b[i] = *(const bf16x8*)
                    &Bb[(size_t)(wn + i * 16 + l16) * 64 + (((kk * 4 + quad) ^ (l16 & 7)) * 8)];
            #pragma unroll
            for (int mi = 0; mi < 4; ++mi)
                #pragma unroll
                for (int ni = 0; ni < NI; ++ni)
                    acc[mi][ni] = __builtin_amdgcn_mfma_f32_16x16x32_bf16(
                        a[mi], b[ni], acc[mi][ni], 0, 0, 0);
        }
    }

    #pragma unroll
    for (int mi = 0; mi < 4; ++mi) {
        #pragma unroll
        for (int ni = 0; ni < NI; ++ni) {
            int col = n0 + wn + ni * 16 + l16;
            float bv = bias ? bias[col] : 0.0f;
            #pragma unroll
            for (int r = 0; r < 4; ++r) {
                int row = m0 + wm + mi * 16 + quad * 4 + r;
                float x = acc[mi][ni][r] + bv;
                if (act) x = x / (1.0f + __expf(-x));
                size_t o = (size_t)row * N + col;
                if (Cf) Cf[o] = x;
                if (Cb) Cb[o] = f32_to_bf16(x);
            }
        }
    }
}

// ---------------------------------------------------------------------------
// All 5 weight transposes in one launch. fp32 (2048 x C) -> bf16 (C x 2048).
// ---------------------------------------------------------------------------
__global__ __launch_bounds__(256) void transpose_all_kernel(
    const float* __restrict__ Wq, const float* __restrict__ Wk,
    const float* __restrict__ Wv, const float* __restrict__ Wr1,
    const float* __restrict__ Wo, short* __restrict__ Wq_t,
    short* __restrict__ Wkv_t, short* __restrict__ Wr1_t,
    short* __restrict__ Wo_t)
{
    __shared__ float tile[32][33];
    int bx = blockIdx.x;
    const float* src; short* dst; int ld, cb;
    if (bx < 64)       { src = Wq;  dst = Wq_t;  ld = 2048; cb = bx; }
    else if (bx < 80)  { src = Wk;  dst = Wkv_t; ld = 512;  cb = bx - 64; }
    else if (bx < 96)  { src = Wv;  dst = Wkv_t + (size_t)512 * 2048; ld = 512; cb = bx - 80; }
    else if (bx < 128) { src = Wr1; dst = Wr1_t; ld = 1024; cb = bx - 96; }
    else               { src = Wo;  dst = Wo_t;  ld = 2048; cb = bx - 128; }
    int c0 = cb * 32, r0 = blockIdx.y * 32;
    int t = threadIdx.x;
    int r = t >> 3, c4 = (t & 7) * 4;
    float4 v = *(const float4*)&src[(size_t)(r0 + r) * ld + c0 + c4];
    tile[r][c4 + 0] = v.x; tile[r][c4 + 1] = v.y;
    tile[r][c4 + 2] = v.z; tile[r][c4 + 3] = v.w;
    __syncthreads();
    short o[4];
    #pragma unroll
    for (int j = 0; j < 4; ++j) o[j] = f32_to_bf16(tile[c4 + j][r]);
    *(uint2*)&dst[(size_t)(c0 + r) * 2048 + r0 + c4] = *(const uint2*)o;
}

// bf16 transpose: src (R x C, ld) -> dst (C x R, ldd). grid (C/32, R/32).
__global__ __launch_bounds__(256) void transpose_bf_kernel(
    const short* __restrict__ src, int ld, short* __restrict__ dst, int ldd)
{
    __shared__ float tile[32][33];
    int r0 = blockIdx.y * 32, c0 = blockIdx.x * 32;
    int x = threadIdx.x & 31, y = threadIdx.x >> 5;
    #pragma unroll
    for (int i = 0; i < 4; ++i)
        tile[y + i * 8][x] = bf16_to_f32(src[(size_t)(r0 + y + i * 8) * ld + c0 + x]);
    __syncthreads();
    #pragma unroll
    for (int i = 0; i < 4; ++i)
        dst[(size_t)(c0 + y + i * 8) * ldd + r0 + x] = f32_to_bf16(tile[x][y + i * 8]);
}

// ---------------------------------------------------------------------------
// Causal prefix EMA (windowed, beta^192~2e-9) + hs -> bf16 conversion.
// ---------------------------------------------------------------------------
__global__ __launch_bounds__(256) void ema_kernel(const float* __restrict__ hs,
                                                  float* __restrict__ l2,
                                                  short* __restrict__ hs_b)
{
    int d = blockIdx.y * 256 + threadIdx.x;
    int t0 = blockIdx.x * 128;
    int ts = t0 - 192; if (ts < 0) ts = 0;
    float m = 0.0f;
    for (int tb = ts; tb < t0; tb += 16) {
        float buf[16];
        #pragma unroll
        for (int j = 0; j < 16; ++j) buf[j] = hs[(size_t)(tb + j) * D_MODEL + d];
        #pragma unroll
        for (int j = 0; j < 16; ++j) m = 0.9f * m + 0.1f * buf[j];
    }
    for (int tb = t0; tb < t0 + 128; tb += 16) {
        float buf[16];
        #pragma unroll
        for (int j = 0; j < 16; ++j) buf[j] = hs[(size_t)(tb + j) * D_MODEL + d];
        #pragma unroll
        for (int j = 0; j < 16; ++j) hs_b[(size_t)(tb + j) * D_MODEL + d] = f32_to_bf16(buf[j]);
        #pragma unroll
        for (int j = 0; j < 16; ++j) { m = 0.9f * m + 0.1f * buf[j]; buf[j] = m; }
        #pragma unroll
        for (int j = 0; j < 16; ++j) l2[(size_t)(tb + j) * D_MODEL + d] = buf[j];
    }
}

// Router head: logits = h @ Wr2 + br2, 2-way softmax. 1 wave/row.
__global__ __launch_bounds__(64) void lam_kernel(
    const short* __restrict__ h, const float* __restrict__ Wr2,
    const float* __restrict__ br2, float* __restrict__ lam)
{
    int t = blockIdx.x;
    int lane = threadIdx.x;
    float z0 = 0.0f, z1 = 0.0f;
    for (int i = lane; i < 1024; i += 64) {
        float hv = bf16_to_f32(h[(size_t)t * 1024 + i]);
        z0 += hv * Wr2[i * 2 + 0];
        z1 += hv * Wr2[i * 2 + 1];
    }
    #pragma unroll
    for (int off = 1; off < 64; off <<= 1) {
        z0 += __shfl_xor(z0, off);
        z1 += __shfl_xor(z1, off);
    }
    if (lane == 0) {
        z0 += br2[0]; z1 += br2[1];
        float mx = fmaxf(z0, z1);
        float e0 = expf(z0 - mx), e1 = expf(z1 - mx);
        float inv = 1.0f / (e0 + e1);
        lam[t * 2 + 0] = e0 * inv;
        lam[t * 2 + 1] = e1 * inv;
    }
}

// fused = lam0*hs + lam1*l2 -> bf16
__global__ void fuse_kernel(const float* __restrict__ hs, const float* __restrict__ l2,
                            const float* __restrict__ lam, short* __restrict__ fused)
{
    int idx = blockIdx.x * blockDim.x + threadIdx.x;
    int t = idx >> 9;
    float a0 = lam[t * 2 + 0], a1 = lam[t * 2 + 1];
    float4 a = ((const float4*)hs)[idx];
    float4 b = ((const float4*)l2)[idx];
    short o[4] = {f32_to_bf16(a0 * a.x + a1 * b.x), f32_to_bf16(a0 * a.y + a1 * b.y),
                  f32_to_bf16(a0 * a.z + a1 * b.z), f32_to_bf16(a0 * a.w + a1 * b.w)};
    *(uint2*)(fused + (size_t)idx * 4) = *(const uint2*)o;
}

// RoPE on q -> (H, T, HD) bf16, with 1/sqrt(HD) folded in.
__global__ void rope_q_kernel(const short* __restrict__ q, short* __restrict__ qr)
{
    int idx = blockIdx.x * blockDim.x + threadIdx.x;   // T*NH*64
    int d = idx & 63;
    int h = (idx >> 6) & 15;
    int t = idx >> 10;
    float fr = (float)t * __expf(-(float)d * 0.14391156831212787f);
    float s, c;
    sincosf(fr, &s, &c);
    const float sc = 0.08838834764831845f;  // 1/sqrt(128)
    const short* src = q + (size_t)t * D_MODEL + h * HD;
    float x1 = bf16_to_f32(src[d]) * sc, x2 = bf16_to_f32(src[d + 64]) * sc;
    short* dst = qr + ((size_t)h * T_SEQ + t) * HD;
    dst[d]      = f32_to_bf16(x1 * c - x2 * s);
    dst[d + 64] = f32_to_bf16(x2 * c + x1 * s);
}

// RoPE on k-half of kv (bf16 T x 1024) -> (KVH, T, HD) bf16.
__global__ void rope_k_kernel(const short* __restrict__ kv, short* __restrict__ kr)
{
    int idx = blockIdx.x * blockDim.x + threadIdx.x;   // T*NKVH*64
    int d = idx & 63;
    int kh = (idx >> 6) & 3;
    int t = idx >> 8;
    float fr = (float)t * __expf(-(float)d * 0.14391156831212787f);
    float s, c;
    sincosf(fr, &s, &c);
    const short* src = kv + (size_t)t * 1024 + kh * HD;
    float x1 = bf16_to_f32(src[d]), x2 = bf16_to_f32(src[d + 64]);
    short* dst = kr + ((size_t)kh * T_SEQ + t) * HD;
    dst[d]      = f32_to_bf16(x1 * c - x2 * s);
    dst[d + 64] = f32_to_bf16(x2 * c + x1 * s);
}

// ---------------------------------------------------------------------------
// Causal flash attention, max-free softmax. Block = (qt, h): 128 q-rows;
// wave = 32 q-rows (two 16-row Q-frag sets) x FULL kv width -> each K/V-frag
// LDS read feeds 2 MFMAs, and P is wave-private (written+read by the same
// wave: lgkmcnt wait only, NO intra-iter barrier). KV tile 64, dbuf
// global_load_lds staging, xor-swizzled chunks. No pairing: makespan =
// slowest block (qt=15, 32 iters); fully-masked waves skip compute.
// LDS 80 KB. Q pre-scaled. K (kvh,T,HD); V^T (kvh,HD,T). Out bf16.
// ---------------------------------------------------------------------------
__global__ __launch_bounds__(256, 1) void attn_kernel(
    const short* __restrict__ Qr, const short* __restrict__ Kr,
    const short* __restrict__ Vt, short* __restrict__ Out)
{
    const int qt = blockIdx.x;          // 0..15 -> q rows [qt*128, +128)
    const int h = blockIdx.y;
    const int kvh = h >> 2;
    const int tid = threadIdx.x;
    const int wave = tid >> 6, lane = tid & 63;
    const int l16 = lane & 15, quad = lane >> 4;

    __shared__ short Klds[2][64 * 128];   // 32 KB: [kv][d], 16B chunks ^(row&15)
    __shared__ short Vlds[2][128 * 64];   // 32 KB: [d][kv], chunks ^(row&7)
    __shared__ short Plds[128 * 64];      // 16 KB: [qrow][kv], chunks ^(row&7)

    const short* kbase = Kr + (size_t)kvh * T_SEQ * HD;
    const short* vbase = Vt + (size_t)kvh * HD * T_SEQ;
    const int qblk = qt * 128;
    const int qrow0 = qblk + wave * 32;
    const int n = 2 * qt + 2;             // KV-64 tiles

    bf16x8 qf[2][4];
    #pragma unroll
    for (int qs = 0; qs < 2; ++qs) {
        const short* qrow = Qr + ((size_t)h * T_SEQ + qrow0 + qs * 16 + l16) * HD;
        #pragma unroll
        for (int kc = 0; kc < 4; ++kc)
            qf[qs][kc] = *(const bf16x8*)&qrow[kc * 32 + quad * 8];
    }
    f32x4 o[2][8] = {};
    float lsum[2][4] = {};

    // stage tile 0
    #pragma unroll
    for (int p = 0; p < 4; ++p) {
        int li = p * 256 + tid;
        int row = li >> 4, gs = (li & 15) ^ (row & 15);
        gl_to_lds16(kbase + (size_t)row * HD + gs * 8,
                    &Klds[0][(size_t)(p * 256 + wave * 64) * 8]);
    }
    #pragma unroll
    for (int p = 0; p < 4; ++p) {
        int li = p * 256 + tid;
        int row = li >> 3, gs = (li & 7) ^ (row & 7);
        gl_to_lds16(vbase + (size_t)row * T_SEQ + gs * 8,
                    &Vlds[0][(size_t)(p * 256 + wave * 64) * 8]);
    }

    for (int t = 0; t < n; ++t) {
        asm volatile("s_waitcnt vmcnt(0)\n\ts_barrier" ::: "memory");

        if (t + 1 < n) {                 // prefetch overlaps compute below
            int kv1 = (t + 1) << 6;
            int nb = (t + 1) & 1;
            const short* ks = kbase + (size_t)kv1 * HD;
            #pragma unroll
            for (int p = 0; p < 4; ++p) {
                int li = p * 256 + tid;
                int row = li >> 4, gs = (li & 15) ^ (row & 15);
                gl_to_lds16(ks + (size_t)row * HD + gs * 8,
                            &Klds[nb][(size_t)(p * 256 + wave * 64) * 8]);
            }
            #pragma unroll
            for (int p = 0; p < 4; ++p) {
                int li = p * 256 + tid;
                int row = li >> 3, gs = (li & 7) ^ (row & 7);
                gl_to_lds16(vbase + (size_t)row * T_SEQ + kv1 + gs * 8,
                            &Vlds[nb][(size_t)(p * 256 + wave * 64) * 8]);
            }
        }

        const int kv0 = t << 6;
        if (qrow0 + 31 >= kv0) {         // wave has unmasked rows
            const short* Kb = Klds[t & 1];
            const short* Vb = Vlds[t & 1];

            // S = Q K^T : 4 kv-subtiles x 4 d-chunks, each K-frag feeds 2 qs
            f32x4 s[2][4];
            #pragma unroll
            for (int qs = 0; qs < 2; ++qs)
                #pragma unroll
                for (int ni = 0; ni < 4; ++ni) s[qs][ni] = (f32x4){0, 0, 0, 0};
            #pragma unroll
            for (int ni = 0; ni < 4; ++ni)
                #pragma unroll
                for (int kc = 0; kc < 4; ++kc) {
                    int row = ni * 16 + l16;
                    bf16x8 b = *(const bf16x8*)
                        &Kb[(size_t)row * 128 + (((kc * 4 + quad) ^ (row & 15)) * 8)];
                    #pragma unroll
                    for (int qs = 0; qs < 2; ++qs)
                        s[qs][ni] = __builtin_amdgcn_mfma_f32_16x16x32_bf16(
                            qf[qs][kc], b, s[qs][ni], 0, 0, 0);
                }

            // max-free softmax; P wave-private in LDS (swizzled chunks)
            if (t >= n - 2) {
                #pragma unroll
                for (int ni = 0; ni < 4; ++ni) {
                    int kvg = kv0 + ni * 16 + l16;
                    #pragma unroll
                    for (int qs = 0; qs < 2; ++qs)
                        #pragma unroll
                        for (int r = 0; r < 4; ++r) {
                            int pr = wave * 32 + qs * 16 + quad * 4 + r;
                            int qg = qblk + pr;
                            float p = (kvg <= qg) ? __expf(s[qs][ni][r]) : 0.0f;
                            lsum[qs][r] += p;
                            int col = ni * 16 + l16;
                            Plds[pr * 64 + (((col >> 3) ^ (pr & 7)) * 8) + (col & 7)]
                                = f32_to_bf16(p);
                        }
                }
            } else {
                #pragma unroll
                for (int ni = 0; ni < 4; ++ni)
                    #pragma unroll
                    for (int qs = 0; qs < 2; ++qs)
                        #pragma unroll
                        for (int r = 0; r < 4; ++r) {
                            int pr = wave * 32 + qs * 16 + quad * 4 + r;
                            float p = __expf(s[qs][ni][r]);
                            lsum[qs][r] += p;
                            int col = ni * 16 + l16;
                            Plds[pr * 64 + (((col >> 3) ^ (pr & 7)) * 8) + (col & 7)]
                                = f32_to_bf16(p);
                        }
            }
            // own writes -> own reads: wave-local visibility, no barrier
            asm volatile("s_waitcnt lgkmcnt(0)" ::: "memory");

            // O += P V : each V-frag feeds 2 qs
            #pragma unroll
            for (int kc2 = 0; kc2 < 2; ++kc2) {
                bf16x8 pa[2];
                #pragma unroll
                for (int qs = 0; qs < 2; ++qs) {
                    int prow = wave * 32 + qs * 16 + l16;
                    pa[qs] = *(const bf16x8*)
                        &Plds[prow * 64 + (((kc2 * 4 + quad) ^ (prow & 7)) * 8)];
                }
                #pragma unroll
                for (int d8 = 0; d8 < 8; ++d8) {
                    int vrow = d8 * 16 + l16;
                    bf16x8 b = *(const bf16x8*)
                        &Vb[(size_t)vrow * 64 + (((kc2 * 4 + quad) ^ (vrow & 7)) * 8)];
                    #pragma unroll
                    for (int qs = 0; qs < 2; ++qs)
                        o[qs][d8] = __builtin_amdgcn_mfma_f32_16x16x32_bf16(
                            pa[qs], b, o[qs][d8], 0, 0, 0);
                }
            }
        }
    }

    // epilogue: 16-lane l reduction (wave covers full kv), normalize, store
    #pragma unroll
    for (int qs = 0; qs < 2; ++qs)
        #pragma unroll
        for (int r = 0; r < 4; ++r) {
            #pragma unroll
            for (int off = 1; off < 16; off <<= 1)
                lsum[qs][r] += __shfl_xor(lsum[qs][r], off);
            lsum[qs][r] = 1.0f / lsum[qs][r];
        }
    #pragma unroll
    for (int qs = 0; qs < 2; ++qs)
        #pragma unroll
        for (int d8 = 0; d8 < 8; ++d8)
            #pragma unroll
            for (int r = 0; r < 4; ++r) {
                int row = qrow0 + qs * 16 + quad * 4 + r;
                Out[(size_t)row * D_MODEL + h * HD + d8 * 16 + l16] =
                    f32_to_bf16(o[qs][d8][r] * lsum[qs][r]);
            }
}

// ---------------------------------------------------------------------------
extern "C" void kernel_launch(void* const* d_in, const int* in_sizes, int n_in,
                              void* d_out, int out_size, void* d_ws, size_t ws_size,
                              hipStream_t stream)
{
    const float* hs  = (const float*)d_in[0];
    const float* Wq  = (const float*)d_in[1];
    const float* Wk  = (const float*)d_in[2];
    const float* Wv  = (const float*)d_in[3];
    const float* Wo  = (const float*)d_in[4];
    const float* Wr1 = (const float*)d_in[5];
    const float* br1 = (const float*)d_in[6];
    const float* Wr2 = (const float*)d_in[7];
    const float* br2 = (const float*)d_in[8];
    float* out = (float*)d_out;

    char* w = (char*)d_ws;
    const size_t MB = 1u << 20;
    float* l2_f     = (float*)(w + 0 * MB);    // 16 MB
    short* hs_bf    = (short*)(w + 16 * MB);   // 8 MB (aliased as attn_bf later)
    short* Wq_t     = (short*)(w + 24 * MB);   // 8 MB
    short* Wkv_t    = (short*)(w + 32 * MB);   // 4 MB  [Wk^T | Wv^T]
    short* Wr1_t    = (short*)(w + 36 * MB);   // 4 MB
    short* Wo_t     = (short*)(w + 40 * MB);   // 8 MB
    short* q_bf     = (short*)(w + 48 * MB);   // 8 MB
    short* h_bf     = (short*)(w + 56 * MB);   // 4 MB
    short* fused_bf = (short*)(w + 60 * MB);   // 8 MB
    short* kv_bf    = (short*)(w + 68 * MB);   // 4 MB
    short* qr       = (short*)(w + 72 * MB);   // 8 MB (H,T,HD), roped+scaled
    short* kr       = (short*)(w + 80 * MB);   // 2 MB (KVH,T,HD), roped
    short* vr       = (short*)(w + 82 * MB);   // 2 MB (KVH,HD,T)
    float* lam_f    = (float*)(w + 84 * MB);   // 16 KB
    short* attn_bf  = hs_bf;                   // alias: hs_bf dead after q-gemm

    transpose_all_kernel<<<dim3(192, 64), 256, 0, stream>>>(
        Wq, Wk, Wv, Wr1, Wo, Wq_t, Wkv_t, Wr1_t, Wo_t);

    ema_kernel<<<dim3(T_SEQ / 128, D_MODEL / 256), 256, 0, stream>>>(hs, l2_f, hs_bf);

    gemm_bt_kernel<128><<<dim3(16, 16), 256, 0, stream>>>(
        hs_bf, Wq_t, nullptr, q_bf, 2048, 2048, 2048, nullptr, 0);

    gemm_bt_kernel<64><<<dim3(8, 32), 256, 0, stream>>>(
        q_bf, Wr1_t, nullptr, h_bf, 2048, 1024, 2048, br1, 1);

    lam_kernel<<<T_SEQ, 64, 0, stream>>>(h_bf, Wr2, br2, lam_f);

    fuse_kernel<<<(T_SEQ * D_MODEL / 4) / 256, 256, 0, stream>>>(hs, l2_f, lam_f, fused_bf);

    gemm_bt_kernel<64><<<dim3(8, 32), 256, 0, stream>>>(
        fused_bf, Wkv_t, nullptr, kv_bf, 2048, 1024, 2048, nullptr, 0);

    rope_q_kernel<<<(T_SEQ * NH * 64) / 256, 256, 0, stream>>>(q_bf, qr);
    rope_k_kernel<<<(T_SEQ * NKVH * 64) / 256, 256, 0, stream>>>(kv_bf, kr);
    transpose_bf_kernel<<<dim3(16, 64), 256, 0, stream>>>(kv_bf + 512, 1024, vr, 2048);

    attn_kernel<<<dim3(16, NH), 256, 0, stream>>>(qr, kr, vr, attn_bf);

    gemm_bt_kernel<128><<<dim3(16, 16), 256, 0, stream>>>(
        attn_bf, Wo_t, out, nullptr, 2048, 2048, 2048, nullptr, 0);
}

// Round 7
// 361.246 us; speedup vs baseline: 1.0694x; 1.0694x over previous
//
#include <hip/hip_runtime.h>
#include <hip/hip_bf16.h>

#define T_SEQ 2048
#define D_MODEL 2048
#define NH 16
#define NKVH 4
#define HD 128

typedef __attribute__((ext_vector_type(8))) short bf16x8;
typedef __attribute__((ext_vector_type(4))) float f32x4;

static __device__ __forceinline__ short f32_to_bf16(float f) {
    unsigned u = __float_as_uint(f);
    u += 0x7fffu + ((u >> 16) & 1u);
    return (short)(u >> 16);
}
static __device__ __forceinline__ float bf16_to_f32(short s) {
    return __uint_as_float(((unsigned)(unsigned short)s) << 16);
}
static __device__ __forceinline__ void gl_to_lds16(const void* g, void* l) {
    __builtin_amdgcn_global_load_lds(
        (const __attribute__((address_space(1))) unsigned int*)g,
        (__attribute__((address_space(3))) unsigned int*)l, 16, 0, 0);
}

// ---------------------------------------------------------------------------
// Pipelined GEMM: A bf16 (M x K), Bt bf16 (N x K), BK=64, BN=128,
// TRIPLE-buffered LDS, prefetch distance 2, s_waitcnt vmcnt(N>0) so the
// next tile's loads stay in flight across the barrier (hipBLASLt pattern:
// per-wave instrs/tile = 8 (BM=128) / 6 (BM=64); waiting vmcnt(that) means
// tile t's loads -- the oldest -- are landed). xor-swizzled 16B chunks.
// ---------------------------------------------------------------------------
template<int BM>
__global__ __launch_bounds__(256) void gemm_bt_kernel(
    const short* __restrict__ A, const short* __restrict__ Bt,
    float* __restrict__ Cf, short* __restrict__ Cb,
    int M, int N, int K, const float* __restrict__ bias, int act)
{
    constexpr int NI = (BM == 128) ? 4 : 2;
    constexpr int ACH = BM / 32;               // A staging instrs per wave/tile
    __shared__ short Alds[3][BM * 64];
    __shared__ short Blds[3][128 * 64];

    const int tid = threadIdx.x;
    const int wave = tid >> 6, lane = tid & 63;
    const int l16 = lane & 15, quad = lane >> 4;
    const int wm = (BM == 128) ? (wave >> 1) * 64 : 0;
    const int wn = (BM == 128) ? (wave & 1) * 64 : wave * 32;
    const int m0 = blockIdx.y * BM, n0 = blockIdx.x * 128;
    const int niter = K >> 6;

    f32x4 acc[4][NI] = {};

    // stage k-tiles 0 and 1
    #pragma unroll
    for (int b0 = 0; b0 < 2; ++b0) {
        int kb = b0 << 6;
        #pragma unroll
        for (int p = 0; p < ACH; ++p) {
            int li = p * 256 + tid;
            int row = li >> 3, sc = li & 7;
            gl_to_lds16(A + (size_t)(m0 + row) * K + kb + ((sc ^ (row & 7)) * 8),
                        &Alds[b0][(size_t)(p * 256 + wave * 64) * 8]);
        }
        #pragma unroll
        for (int p = 0; p < 4; ++p) {
            int li = p * 256 + tid;
            int row = li >> 3, sc = li & 7;
            gl_to_lds16(Bt + (size_t)(n0 + row) * K + kb + ((sc ^ (row & 7)) * 8),
                        &Blds[b0][(size_t)(p * 256 + wave * 64) * 8]);
        }
    }

    for (int t = 0; t < niter; ++t) {
        // tile t landed (oldest loads); tile t+1 stays in flight
        if (t + 1 < niter) {
            if (BM == 128) asm volatile("s_waitcnt vmcnt(8)\n\ts_barrier" ::: "memory");
            else           asm volatile("s_waitcnt vmcnt(6)\n\ts_barrier" ::: "memory");
        } else {
            asm volatile("s_waitcnt vmcnt(0)\n\ts_barrier" ::: "memory");
        }

        if (t + 2 < niter) {               // prefetch t+2 into rotated buffer
            int k1 = (t + 2) << 6;
            int nb = (t + 2) % 3;
            #pragma unroll
            for (int p = 0; p < ACH; ++p) {
                int li = p * 256 + tid;
                int row = li >> 3, sc = li & 7;
                gl_to_lds16(A + (size_t)(m0 + row) * K + k1 + ((sc ^ (row & 7)) * 8),
                            &Alds[nb][(size_t)(p * 256 + wave * 64) * 8]);
            }
            #pragma unroll
            for (int p = 0; p < 4; ++p) {
                int li = p * 256 + tid;
                int row = li >> 3, sc = li & 7;
                gl_to_lds16(Bt + (size_t)(n0 + row) * K + k1 + ((sc ^ (row & 7)) * 8),
                            &Blds[nb][(size_t)(p * 256 + wave * 64) * 8]);
            }
        }

        const short* Ab = Alds[t % 3];
        const short* Bb = Blds[t % 3];
        #pragma unroll
        for (int kk = 0; kk < 2; ++kk) {
            bf16x8 a[4], b[NI];
            #pragma unroll
            for (int i = 0; i < 4; ++i)
                a[i] = *(const bf16x8*)
                    &Ab[(size_t)(wm + i * 16 + l16) * 64 + (((kk * 4 + quad) ^ (l16 & 7)) * 8)];
            #pragma unroll
            for (int i = 0; i < NI; ++i)
                b[i] = *(const bf16x8*)
                    &Bb[(size_t)(wn + i * 16 + l16) * 64 + (((kk * 4 + quad) ^ (l16 & 7)) * 8)];
            #pragma unroll
            for (int mi = 0; mi < 4; ++mi)
                #pragma unroll
                for (int ni = 0; ni < NI; ++ni)
                    acc[mi][ni] = __builtin_amdgcn_mfma_f32_16x16x32_bf16(
                        a[mi], b[ni], acc[mi][ni], 0, 0, 0);
        }
    }

    #pragma unroll
    for (int mi = 0; mi < 4; ++mi) {
        #pragma unroll
        for (int ni = 0; ni < NI; ++ni) {
            int col = n0 + wn + ni * 16 + l16;
            float bv = bias ? bias[col] : 0.0f;
            #pragma unroll
            for (int r = 0; r < 4; ++r) {
                int row = m0 + wm + mi * 16 + quad * 4 + r;
                float x = acc[mi][ni][r] + bv;
                if (act) x = x / (1.0f + __expf(-x));
                size_t o = (size_t)row * N + col;
                if (Cf) Cf[o] = x;
                if (Cb) Cb[o] = f32_to_bf16(x);
            }
        }
    }
}

// ---------------------------------------------------------------------------
// All 5 weight transposes in one launch. fp32 (2048 x C) -> bf16 (C x 2048).
// ---------------------------------------------------------------------------
__global__ __launch_bounds__(256) void transpose_all_kernel(
    const float* __restrict__ Wq, const float* __restrict__ Wk,
    const float* __restrict__ Wv, const float* __restrict__ Wr1,
    const float* __restrict__ Wo, short* __restrict__ Wq_t,
    short* __restrict__ Wkv_t, short* __restrict__ Wr1_t,
    short* __restrict__ Wo_t)
{
    __shared__ float tile[32][33];
    int bx = blockIdx.x;
    const float* src; short* dst; int ld, cb;
    if (bx < 64)       { src = Wq;  dst = Wq_t;  ld = 2048; cb = bx; }
    else if (bx < 80)  { src = Wk;  dst = Wkv_t; ld = 512;  cb = bx - 64; }
    else if (bx < 96)  { src = Wv;  dst = Wkv_t + (size_t)512 * 2048; ld = 512; cb = bx - 80; }
    else if (bx < 128) { src = Wr1; dst = Wr1_t; ld = 1024; cb = bx - 96; }
    else               { src = Wo;  dst = Wo_t;  ld = 2048; cb = bx - 128; }
    int c0 = cb * 32, r0 = blockIdx.y * 32;
    int t = threadIdx.x;
    int r = t >> 3, c4 = (t & 7) * 4;
    float4 v = *(const float4*)&src[(size_t)(r0 + r) * ld + c0 + c4];
    tile[r][c4 + 0] = v.x; tile[r][c4 + 1] = v.y;
    tile[r][c4 + 2] = v.z; tile[r][c4 + 3] = v.w;
    __syncthreads();
    short o[4];
    #pragma unroll
    for (int j = 0; j < 4; ++j) o[j] = f32_to_bf16(tile[c4 + j][r]);
    *(uint2*)&dst[(size_t)(c0 + r) * 2048 + r0 + c4] = *(const uint2*)o;
}

// bf16 transpose: src (R x C, ld) -> dst (C x R, ldd). grid (C/32, R/32).
__global__ __launch_bounds__(256) void transpose_bf_kernel(
    const short* __restrict__ src, int ld, short* __restrict__ dst, int ldd)
{
    __shared__ float tile[32][33];
    int r0 = blockIdx.y * 32, c0 = blockIdx.x * 32;
    int x = threadIdx.x & 31, y = threadIdx.x >> 5;
    #pragma unroll
    for (int i = 0; i < 4; ++i)
        tile[y + i * 8][x] = bf16_to_f32(src[(size_t)(r0 + y + i * 8) * ld + c0 + x]);
    __syncthreads();
    #pragma unroll
    for (int i = 0; i < 4; ++i)
        dst[(size_t)(c0 + y + i * 8) * ldd + r0 + x] = f32_to_bf16(tile[x][y + i * 8]);
}

// ---------------------------------------------------------------------------
// Causal prefix EMA (windowed, beta^192~2e-9) + hs -> bf16 conversion.
// ---------------------------------------------------------------------------
__global__ __launch_bounds__(256) void ema_kernel(const float* __restrict__ hs,
                                                  float* __restrict__ l2,
                                                  short* __restrict__ hs_b)
{
    int d = blockIdx.y * 256 + threadIdx.x;
    int t0 = blockIdx.x * 128;
    int ts = t0 - 192; if (ts < 0) ts = 0;
    float m = 0.0f;
    for (int tb = ts; tb < t0; tb += 16) {
        float buf[16];
        #pragma unroll
        for (int j = 0; j < 16; ++j) buf[j] = hs[(size_t)(tb + j) * D_MODEL + d];
        #pragma unroll
        for (int j = 0; j < 16; ++j) m = 0.9f * m + 0.1f * buf[j];
    }
    for (int tb = t0; tb < t0 + 128; tb += 16) {
        float buf[16];
        #pragma unroll
        for (int j = 0; j < 16; ++j) buf[j] = hs[(size_t)(tb + j) * D_MODEL + d];
        #pragma unroll
        for (int j = 0; j < 16; ++j) hs_b[(size_t)(tb + j) * D_MODEL + d] = f32_to_bf16(buf[j]);
        #pragma unroll
        for (int j = 0; j < 16; ++j) { m = 0.9f * m + 0.1f * buf[j]; buf[j] = m; }
        #pragma unroll
        for (int j = 0; j < 16; ++j) l2[(size_t)(tb + j) * D_MODEL + d] = buf[j];
    }
}

// Router head: logits = h @ Wr2 + br2, 2-way softmax. 1 wave/row.
__global__ __launch_bounds__(64) void lam_kernel(
    const short* __restrict__ h, const float* __restrict__ Wr2,
    const float* __restrict__ br2, float* __restrict__ lam)
{
    int t = blockIdx.x;
    int lane = threadIdx.x;
    float z0 = 0.0f, z1 = 0.0f;
    for (int i = lane; i < 1024; i += 64) {
        float hv = bf16_to_f32(h[(size_t)t * 1024 + i]);
        z0 += hv * Wr2[i * 2 + 0];
        z1 += hv * Wr2[i * 2 + 1];
    }
    #pragma unroll
    for (int off = 1; off < 64; off <<= 1) {
        z0 += __shfl_xor(z0, off);
        z1 += __shfl_xor(z1, off);
    }
    if (lane == 0) {
        z0 += br2[0]; z1 += br2[1];
        float mx = fmaxf(z0, z1);
        float e0 = expf(z0 - mx), e1 = expf(z1 - mx);
        float inv = 1.0f / (e0 + e1);
        lam[t * 2 + 0] = e0 * inv;
        lam[t * 2 + 1] = e1 * inv;
    }
}

// fused = lam0*hs + lam1*l2 -> bf16
__global__ void fuse_kernel(const float* __restrict__ hs, const float* __restrict__ l2,
                            const float* __restrict__ lam, short* __restrict__ fused)
{
    int idx = blockIdx.x * blockDim.x + threadIdx.x;
    int t = idx >> 9;
    float a0 = lam[t * 2 + 0], a1 = lam[t * 2 + 1];
    float4 a = ((const float4*)hs)[idx];
    float4 b = ((const float4*)l2)[idx];
    short o[4] = {f32_to_bf16(a0 * a.x + a1 * b.x), f32_to_bf16(a0 * a.y + a1 * b.y),
                  f32_to_bf16(a0 * a.z + a1 * b.z), f32_to_bf16(a0 * a.w + a1 * b.w)};
    *(uint2*)(fused + (size_t)idx * 4) = *(const uint2*)o;
}

// RoPE on q -> (H, T, HD) bf16, with 1/sqrt(HD) folded in.
__global__ void rope_q_kernel(const short* __restrict__ q, short* __restrict__ qr)
{
    int idx = blockIdx.x * blockDim.x + threadIdx.x;   // T*NH*64
    int d = idx & 63;
    int h = (idx >> 6) & 15;
    int t = idx >> 10;
    float fr = (float)t * __expf(-(float)d * 0.14391156831212787f);
    float s, c;
    sincosf(fr, &s, &c);
    const float sc = 0.08838834764831845f;  // 1/sqrt(128)
    const short* src = q + (size_t)t * D_MODEL + h * HD;
    float x1 = bf16_to_f32(src[d]) * sc, x2 = bf16_to_f32(src[d + 64]) * sc;
    short* dst = qr + ((size_t)h * T_SEQ + t) * HD;
    dst[d]      = f32_to_bf16(x1 * c - x2 * s);
    dst[d + 64] = f32_to_bf16(x2 * c + x1 * s);
}

// RoPE on k-half of kv (bf16 T x 1024) -> (KVH, T, HD) bf16.
__global__ void rope_k_kernel(const short* __restrict__ kv, short* __restrict__ kr)
{
    int idx = blockIdx.x * blockDim.x + threadIdx.x;   // T*NKVH*64
    int d = idx & 63;
    int kh = (idx >> 6) & 3;
    int t = idx >> 8;
    float fr = (float)t * __expf(-(float)d * 0.14391156831212787f);
    float s, c;
    sincosf(fr, &s, &c);
    const short* src = kv + (size_t)t * 1024 + kh * HD;
    float x1 = bf16_to_f32(src[d]), x2 = bf16_to_f32(src[d + 64]);
    short* dst = kr + ((size_t)kh * T_SEQ + t) * HD;
    dst[d]      = f32_to_bf16(x1 * c - x2 * s);
    dst[d + 64] = f32_to_bf16(x2 * c + x1 * s);
}

// ---------------------------------------------------------------------------
// Causal flash attention (R4 structure + deep pipeline): max-free softmax,
// paired q-tiles (block does qt=pi then 31-pi: exactly 33 KV-64 iters),
// 64 q-rows/block, wave = 16 q-rows x full kv (P wave-private, lgkmcnt-only).
// KV-64 tiles, TRIPLE-buffered global_load_lds, prefetch distance 2,
// s_waitcnt vmcnt(8) (8 staging instrs/wave/tile) -- no full drain.
// Q pre-scaled. K (kvh,T,HD); V^T (kvh,HD,T). Out bf16 (T, H*HD).
// ---------------------------------------------------------------------------
static __device__ __forceinline__ void attn_stage(
    const short* kbase, const short* vbase, int kv0,
    short* Kb, short* Vb, int tid, int wave)
{
    const short* ks = kbase + (size_t)kv0 * HD;
    #pragma unroll
    for (int p = 0; p < 4; ++p) {
        int li = p * 256 + tid;
        int row = li >> 4, gs = (li & 15) ^ (row & 15);
        gl_to_lds16(ks + (size_t)row * HD + gs * 8,
                    Kb + (size_t)(p * 256 + wave * 64) * 8);
    }
    #pragma unroll
    for (int p = 0; p < 4; ++p) {
        int li = p * 256 + tid;
        int row = li >> 3, gs = (li & 7) ^ (row & 7);
        gl_to_lds16(vbase + (size_t)row * T_SEQ + kv0 + gs * 8,
                    Vb + (size_t)(p * 256 + wave * 64) * 8);
    }
}

__global__ __launch_bounds__(256, 1) void attn_kernel(
    const short* __restrict__ Qr, const short* __restrict__ Kr,
    const short* __restrict__ Vt, short* __restrict__ Out)
{
    const int pi = blockIdx.x;          // 0..15
    const int h = blockIdx.y;
    const int kvh = h >> 2;
    const int tid = threadIdx.x;
    const int wave = tid >> 6, lane = tid & 63;
    const int l16 = lane & 15, quad = lane >> 4;

    __shared__ short Klds[3][64 * 128];   // 48 KB: [kv][d], chunks ^(row&15)
    __shared__ short Vlds[3][128 * 64];   // 48 KB: [d][kv], chunks ^(row&7)
    __shared__ short Plds[4][16][72];     // 9 KB per-wave P (pad 72: 144B rows)

    const short* kbase = Kr + (size_t)kvh * T_SEQ * HD;
    const short* vbase = Vt + (size_t)kvh * HD * T_SEQ;

    for (int ph = 0; ph < 2; ++ph) {
        const int qt = ph ? (31 - pi) : pi;
        const int qbase = qt * 64 + wave * 16;
        const int n = qt + 1;             // KV-64 tiles this phase

        bf16x8 qf[4];
        {
            const short* qrow = Qr + ((size_t)h * T_SEQ + qbase + l16) * HD;
            #pragma unroll
            for (int kc = 0; kc < 4; ++kc)
                qf[kc] = *(const bf16x8*)&qrow[kc * 32 + quad * 8];
        }
        f32x4 o[8] = {};
        float lsum[4] = {0.0f, 0.0f, 0.0f, 0.0f};

        __syncthreads();   // previous phase fully done with LDS

        attn_stage(kbase, vbase, 0, Klds[0], Vlds[0], tid, wave);
        if (n > 1) attn_stage(kbase, vbase, 64, Klds[1], Vlds[1], tid, wave);

        for (int t = 0; t < n; ++t) {
            if (t + 1 < n)
                asm volatile("s_waitcnt vmcnt(8)\n\ts_barrier" ::: "memory");
            else
                asm volatile("s_waitcnt vmcnt(0)\n\ts_barrier" ::: "memory");

            if (t + 2 < n)
                attn_stage(kbase, vbase, (t + 2) << 6,
                           Klds[(t + 2) % 3], Vlds[(t + 2) % 3], tid, wave);

            const short* Kb = Klds[t % 3];
            const short* Vb = Vlds[t % 3];

            // S = Q K^T : 4 kv-subtiles x 4 d-chunks
            f32x4 s[4];
            #pragma unroll
            for (int ni = 0; ni < 4; ++ni) s[ni] = (f32x4){0, 0, 0, 0};
            #pragma unroll
            for (int ni = 0; ni < 4; ++ni)
                #pragma unroll
                for (int kc = 0; kc < 4; ++kc) {
                    int row = ni * 16 + l16;
                    bf16x8 b = *(const bf16x8*)
                        &Kb[(size_t)row * 128 + (((kc * 4 + quad) ^ (row & 15)) * 8)];
                    s[ni] = __builtin_amdgcn_mfma_f32_16x16x32_bf16(qf[kc], b, s[ni], 0, 0, 0);
                }

            // max-free softmax: p = exp(s), per-lane l partials; P wave-private
            if (t == n - 1) {
                int kvg0 = t << 6;
                #pragma unroll
                for (int ni = 0; ni < 4; ++ni) {
                    int kvg = kvg0 + ni * 16 + l16;
                    #pragma unroll
                    for (int r = 0; r < 4; ++r) {
                        int qg = qbase + quad * 4 + r;
                        float p = (kvg <= qg) ? __expf(s[ni][r]) : 0.0f;
                        lsum[r] += p;
                        Plds[wave][quad * 4 + r][ni * 16 + l16] = f32_to_bf16(p);
                    }
                }
            } else {
                #pragma unroll
                for (int ni = 0; ni < 4; ++ni)
                    #pragma unroll
                    for (int r = 0; r < 4; ++r) {
                        float p = __expf(s[ni][r]);
                        lsum[r] += p;
                        Plds[wave][quad * 4 + r][ni * 16 + l16] = f32_to_bf16(p);
                    }
            }
            // own writes -> own reads: wave-local, no barrier, keep vmcnt alive
            asm volatile("s_waitcnt lgkmcnt(0)" ::: "memory");

            // O += P V : 2 k-chunks x 8 d-subtiles
            #pragma unroll
            for (int kc2 = 0; kc2 < 2; ++kc2) {
                bf16x8 pa = *(const bf16x8*)&Plds[wave][l16][kc2 * 32 + quad * 8];
                #pragma unroll
                for (int d8 = 0; d8 < 8; ++d8) {
                    int vrow = d8 * 16 + l16;
                    bf16x8 b = *(const bf16x8*)
                        &Vb[(size_t)vrow * 64 + (((kc2 * 4 + quad) ^ (vrow & 7)) * 8)];
                    o[d8] = __builtin_amdgcn_mfma_f32_16x16x32_bf16(pa, b, o[d8], 0, 0, 0);
                }
            }
        }

        // epilogue: one 16-lane l reduction, then normalize + store
        #pragma unroll
        for (int r = 0; r < 4; ++r) {
            #pragma unroll
            for (int off = 1; off < 16; off <<= 1)
                lsum[r] += __shfl_xor(lsum[r], off);
            lsum[r] = 1.0f / lsum[r];
        }
        #pragma unroll
        for (int d8 = 0; d8 < 8; ++d8)
            #pragma unroll
            for (int r = 0; r < 4; ++r) {
                int row = qbase + quad * 4 + r;
                Out[(size_t)row * D_MODEL + h * HD + d8 * 16 + l16] =
                    f32_to_bf16(o[d8][r] * lsum[r]);
            }
    }
}

// ---------------------------------------------------------------------------
extern "C" void kernel_launch(void* const* d_in, const int* in_sizes, int n_in,
                              void* d_out, int out_size, void* d_ws, size_t ws_size,
                              hipStream_t stream)
{
    const float* hs  = (const float*)d_in[0];
    const float* Wq  = (const float*)d_in[1];
    const float* Wk  = (const float*)d_in[2];
    const float* Wv  = (const float*)d_in[3];
    const float* Wo  = (const float*)d_in[4];
    const float* Wr1 = (const float*)d_in[5];
    const float* br1 = (const float*)d_in[6];
    const float* Wr2 = (const float*)d_in[7];
    const float* br2 = (const float*)d_in[8];
    float* out = (float*)d_out;

    char* w = (char*)d_ws;
    const size_t MB = 1u << 20;
    float* l2_f     = (float*)(w + 0 * MB);    // 16 MB
    short* hs_bf    = (short*)(w + 16 * MB);   // 8 MB (aliased as attn_bf later)
    short* Wq_t     = (short*)(w + 24 * MB);   // 8 MB
    short* Wkv_t    = (short*)(w + 32 * MB);   // 4 MB  [Wk^T | Wv^T]
    short* Wr1_t    = (short*)(w + 36 * MB);   // 4 MB
    short* Wo_t     = (short*)(w + 40 * MB);   // 8 MB
    short* q_bf     = (short*)(w + 48 * MB);   // 8 MB
    short* h_bf     = (short*)(w + 56 * MB);   // 4 MB
    short* fused_bf = (short*)(w + 60 * MB);   // 8 MB
    short* kv_bf    = (short*)(w + 68 * MB);   // 4 MB
    short* qr       = (short*)(w + 72 * MB);   // 8 MB (H,T,HD), roped+scaled
    short* kr       = (short*)(w + 80 * MB);   // 2 MB (KVH,T,HD), roped
    short* vr       = (short*)(w + 82 * MB);   // 2 MB (KVH,HD,T)
    float* lam_f    = (float*)(w + 84 * MB);   // 16 KB
    short* attn_bf  = hs_bf;                   // alias: hs_bf dead after q-gemm

    transpose_all_kernel<<<dim3(192, 64), 256, 0, stream>>>(
        Wq, Wk, Wv, Wr1, Wo, Wq_t, Wkv_t, Wr1_t, Wo_t);

    ema_kernel<<<dim3(T_SEQ / 128, D_MODEL / 256), 256, 0, stream>>>(hs, l2_f, hs_bf);

    gemm_bt_kernel<128><<<dim3(16, 16), 256, 0, stream>>>(
        hs_bf, Wq_t, nullptr, q_bf, 2048, 2048, 2048, nullptr, 0);

    gemm_bt_kernel<64><<<dim3(8, 32), 256, 0, stream>>>(
        q_bf, Wr1_t, nullptr, h_bf, 2048, 1024, 2048, br1, 1);

    lam_kernel<<<T_SEQ, 64, 0, stream>>>(h_bf, Wr2, br2, lam_f);

    fuse_kernel<<<(T_SEQ * D_MODEL / 4) / 256, 256, 0, stream>>>(hs, l2_f, lam_f, fused_bf);

    gemm_bt_kernel<64><<<dim3(8, 32), 256, 0, stream>>>(
        fused_bf, Wkv_t, nullptr, kv_bf, 2048, 1024, 2048, nullptr, 0);

    rope_q_kernel<<<(T_SEQ * NH * 64) / 256, 256, 0, stream>>>(q_bf, qr);
    rope_k_kernel<<<(T_SEQ * NKVH * 64) / 256, 256, 0, stream>>>(kv_bf, kr);
    transpose_bf_kernel<<<dim3(16, 64), 256, 0, stream>>>(kv_bf + 512, 1024, vr, 2048);

    attn_kernel<<<dim3(16, NH), 256, 0, stream>>>(qr, kr, vr, attn_bf);

    gemm_bt_kernel<128><<<dim3(16, 16), 256, 0, stream>>>(
        attn_bf, Wo_t, out, nullptr, 2048, 2048, 2048, nullptr, 0);
}

// Round 8
// 315.831 us; speedup vs baseline: 1.2231x; 1.1438x over previous
//
#include <hip/hip_runtime.h>
#include <hip/hip_bf16.h>

#define T_SEQ 2048
#define D_MODEL 2048
#define NH 16
#define NKVH 4
#define HD 128

typedef __attribute__((ext_vector_type(8))) short bf16x8;
typedef __attribute__((ext_vector_type(4))) float f32x4;

static __device__ __forceinline__ short f32_to_bf16(float f) {
    unsigned u = __float_as_uint(f);
    u += 0x7fffu + ((u >> 16) & 1u);
    return (short)(u >> 16);
}
static __device__ __forceinline__ float bf16_to_f32(short s) {
    return __uint_as_float(((unsigned)(unsigned short)s) << 16);
}
static __device__ __forceinline__ void gl_to_lds16(const void* g, void* l) {
    __builtin_amdgcn_global_load_lds(
        (const __attribute__((address_space(1))) unsigned int*)g,
        (__attribute__((address_space(3))) unsigned int*)l, 16, 0, 0);
}

// ---------------------------------------------------------------------------
// Pipelined GEMM, R4-proven loop (dbuf, vmcnt(0)+barrier, prefetch-after-
// barrier, xor-swizzle) but BM=64 so grid = (N/BN)*(M/64) = 512 blocks
// = 2 blocks/CU: inter-block wave overlap absorbs the barrier drain that
// capped every 1-block/CU variant (R3/R4/R6/R7) at ~2us/iter.
// BN=128: wave = 64x32 (NI=2). BN=64: wave = 64x16 (NI=1). LDS 48/32 KB.
// ---------------------------------------------------------------------------
template<int BN>
__global__ __launch_bounds__(256, 2) void gemm_bt_kernel(
    const short* __restrict__ A, const short* __restrict__ Bt,
    float* __restrict__ Cf, short* __restrict__ Cb,
    int M, int N, int K, const float* __restrict__ bias, int act)
{
    constexpr int NI = BN / 64;                // 2 or 1
    constexpr int BCH = BN / 32;               // B staging instrs/wave (4 or 2)
    __shared__ short Alds[2][64 * 64];
    __shared__ short Blds[2][BN * 64];

    const int tid = threadIdx.x;
    const int wave = tid >> 6, lane = tid & 63;
    const int l16 = lane & 15, quad = lane >> 4;
    const int wn = wave * (BN / 4);
    const int m0 = blockIdx.y * 64, n0 = blockIdx.x * BN;
    const int niter = K >> 6;

    f32x4 acc[4][NI] = {};

    #pragma unroll
    for (int p = 0; p < 2; ++p) {
        int li = p * 256 + tid;
        int row = li >> 3, sc = li & 7;
        gl_to_lds16(A + (size_t)(m0 + row) * K + ((sc ^ (row & 7)) * 8),
                    &Alds[0][(size_t)(p * 256 + wave * 64) * 8]);
    }
    #pragma unroll
    for (int p = 0; p < BCH; ++p) {
        int li = p * 256 + tid;
        int row = li >> 3, sc = li & 7;
        gl_to_lds16(Bt + (size_t)(n0 + row) * K + ((sc ^ (row & 7)) * 8),
                    &Blds[0][(size_t)(p * 256 + wave * 64) * 8]);
    }

    for (int t = 0; t < niter; ++t) {
        asm volatile("s_waitcnt vmcnt(0)\n\ts_barrier" ::: "memory");

        if (t + 1 < niter) {               // prefetch overlaps compute below
            int k1 = (t + 1) << 6;
            int nb = (t + 1) & 1;
            #pragma unroll
            for (int p = 0; p < 2; ++p) {
                int li = p * 256 + tid;
                int row = li >> 3, sc = li & 7;
                gl_to_lds16(A + (size_t)(m0 + row) * K + k1 + ((sc ^ (row & 7)) * 8),
                            &Alds[nb][(size_t)(p * 256 + wave * 64) * 8]);
            }
            #pragma unroll
            for (int p = 0; p < BCH; ++p) {
                int li = p * 256 + tid;
                int row = li >> 3, sc = li & 7;
                gl_to_lds16(Bt + (size_t)(n0 + row) * K + k1 + ((sc ^ (row & 7)) * 8),
                            &Blds[nb][(size_t)(p * 256 + wave * 64) * 8]);
            }
        }

        const short* Ab = Alds[t & 1];
        const short* Bb = Blds[t & 1];
        #pragma unroll
        for (int kk = 0; kk < 2; ++kk) {
            bf16x8 a[4], b[NI];
            #pragma unroll
            for (int i = 0; i < 4; ++i)
                a[i] = *(const bf16x8*)
                    &Ab[(size_t)(i * 16 + l16) * 64 + (((kk * 4 + quad) ^ (l16 & 7)) * 8)];
            #pragma unroll
            for (int i = 0; i < NI; ++i)
                b[i] = *(const bf16x8*)
                    &Bb[(size_t)(wn + i * 16 + l16) * 64 + (((kk * 4 + quad) ^ (l16 & 7)) * 8)];
            #pragma unroll
            for (int mi = 0; mi < 4; ++mi)
                #pragma unroll
                for (int ni = 0; ni < NI; ++ni)
                    acc[mi][ni] = __builtin_amdgcn_mfma_f32_16x16x32_bf16(
                        a[mi], b[ni], acc[mi][ni], 0, 0, 0);
        }
    }

    #pragma unroll
    for (int mi = 0; mi < 4; ++mi) {
        #pragma unroll
        for (int ni = 0; ni < NI; ++ni) {
            int col = n0 + wn + ni * 16 + l16;
            float bv = bias ? bias[col] : 0.0f;
            #pragma unroll
            for (int r = 0; r < 4; ++r) {
                int row = m0 + mi * 16 + quad * 4 + r;
                float x = acc[mi][ni][r] + bv;
                if (act) x = x / (1.0f + __expf(-x));
                size_t o = (size_t)row * N + col;
                if (Cf) Cf[o] = x;
                if (Cb) Cb[o] = f32_to_bf16(x);
            }
        }
    }
}

// ---------------------------------------------------------------------------
// All 5 weight transposes in one launch. fp32 (2048 x C) -> bf16 (C x 2048).
// ---------------------------------------------------------------------------
__global__ __launch_bounds__(256) void transpose_all_kernel(
    const float* __restrict__ Wq, const float* __restrict__ Wk,
    const float* __restrict__ Wv, const float* __restrict__ Wr1,
    const float* __restrict__ Wo, short* __restrict__ Wq_t,
    short* __restrict__ Wkv_t, short* __restrict__ Wr1_t,
    short* __restrict__ Wo_t)
{
    __shared__ float tile[32][33];
    int bx = blockIdx.x;
    const float* src; short* dst; int ld, cb;
    if (bx < 64)       { src = Wq;  dst = Wq_t;  ld = 2048; cb = bx; }
    else if (bx < 80)  { src = Wk;  dst = Wkv_t; ld = 512;  cb = bx - 64; }
    else if (bx < 96)  { src = Wv;  dst = Wkv_t + (size_t)512 * 2048; ld = 512; cb = bx - 80; }
    else if (bx < 128) { src = Wr1; dst = Wr1_t; ld = 1024; cb = bx - 96; }
    else               { src = Wo;  dst = Wo_t;  ld = 2048; cb = bx - 128; }
    int c0 = cb * 32, r0 = blockIdx.y * 32;
    int t = threadIdx.x;
    int r = t >> 3, c4 = (t & 7) * 4;
    float4 v = *(const float4*)&src[(size_t)(r0 + r) * ld + c0 + c4];
    tile[r][c4 + 0] = v.x; tile[r][c4 + 1] = v.y;
    tile[r][c4 + 2] = v.z; tile[r][c4 + 3] = v.w;
    __syncthreads();
    short o[4];
    #pragma unroll
    for (int j = 0; j < 4; ++j) o[j] = f32_to_bf16(tile[c4 + j][r]);
    *(uint2*)&dst[(size_t)(c0 + r) * 2048 + r0 + c4] = *(const uint2*)o;
}

// bf16 transpose: src (R x C, ld) -> dst (C x R, ldd). grid (C/32, R/32).
__global__ __launch_bounds__(256) void transpose_bf_kernel(
    const short* __restrict__ src, int ld, short* __restrict__ dst, int ldd)
{
    __shared__ float tile[32][33];
    int r0 = blockIdx.y * 32, c0 = blockIdx.x * 32;
    int x = threadIdx.x & 31, y = threadIdx.x >> 5;
    #pragma unroll
    for (int i = 0; i < 4; ++i)
        tile[y + i * 8][x] = bf16_to_f32(src[(size_t)(r0 + y + i * 8) * ld + c0 + x]);
    __syncthreads();
    #pragma unroll
    for (int i = 0; i < 4; ++i)
        dst[(size_t)(c0 + y + i * 8) * ldd + r0 + x] = f32_to_bf16(tile[x][y + i * 8]);
}

// ---------------------------------------------------------------------------
// Causal prefix EMA (windowed, beta^192~2e-9) + hs -> bf16 conversion.
// ---------------------------------------------------------------------------
__global__ __launch_bounds__(256) void ema_kernel(const float* __restrict__ hs,
                                                  float* __restrict__ l2,
                                                  short* __restrict__ hs_b)
{
    int d = blockIdx.y * 256 + threadIdx.x;
    int t0 = blockIdx.x * 128;
    int ts = t0 - 192; if (ts < 0) ts = 0;
    float m = 0.0f;
    for (int tb = ts; tb < t0; tb += 16) {
        float buf[16];
        #pragma unroll
        for (int j = 0; j < 16; ++j) buf[j] = hs[(size_t)(tb + j) * D_MODEL + d];
        #pragma unroll
        for (int j = 0; j < 16; ++j) m = 0.9f * m + 0.1f * buf[j];
    }
    for (int tb = t0; tb < t0 + 128; tb += 16) {
        float buf[16];
        #pragma unroll
        for (int j = 0; j < 16; ++j) buf[j] = hs[(size_t)(tb + j) * D_MODEL + d];
        #pragma unroll
        for (int j = 0; j < 16; ++j) hs_b[(size_t)(tb + j) * D_MODEL + d] = f32_to_bf16(buf[j]);
        #pragma unroll
        for (int j = 0; j < 16; ++j) { m = 0.9f * m + 0.1f * buf[j]; buf[j] = m; }
        #pragma unroll
        for (int j = 0; j < 16; ++j) l2[(size_t)(tb + j) * D_MODEL + d] = buf[j];
    }
}

// Router head: logits = h @ Wr2 + br2, 2-way softmax. 1 wave/row.
__global__ __launch_bounds__(64) void lam_kernel(
    const short* __restrict__ h, const float* __restrict__ Wr2,
    const float* __restrict__ br2, float* __restrict__ lam)
{
    int t = blockIdx.x;
    int lane = threadIdx.x;
    float z0 = 0.0f, z1 = 0.0f;
    for (int i = lane; i < 1024; i += 64) {
        float hv = bf16_to_f32(h[(size_t)t * 1024 + i]);
        z0 += hv * Wr2[i * 2 + 0];
        z1 += hv * Wr2[i * 2 + 1];
    }
    #pragma unroll
    for (int off = 1; off < 64; off <<= 1) {
        z0 += __shfl_xor(z0, off);
        z1 += __shfl_xor(z1, off);
    }
    if (lane == 0) {
        z0 += br2[0]; z1 += br2[1];
        float mx = fmaxf(z0, z1);
        float e0 = expf(z0 - mx), e1 = expf(z1 - mx);
        float inv = 1.0f / (e0 + e1);
        lam[t * 2 + 0] = e0 * inv;
        lam[t * 2 + 1] = e1 * inv;
    }
}

// fused = lam0*hs + lam1*l2 -> bf16
__global__ void fuse_kernel(const float* __restrict__ hs, const float* __restrict__ l2,
                            const float* __restrict__ lam, short* __restrict__ fused)
{
    int idx = blockIdx.x * blockDim.x + threadIdx.x;
    int t = idx >> 9;
    float a0 = lam[t * 2 + 0], a1 = lam[t * 2 + 1];
    float4 a = ((const float4*)hs)[idx];
    float4 b = ((const float4*)l2)[idx];
    short o[4] = {f32_to_bf16(a0 * a.x + a1 * b.x), f32_to_bf16(a0 * a.y + a1 * b.y),
                  f32_to_bf16(a0 * a.z + a1 * b.z), f32_to_bf16(a0 * a.w + a1 * b.w)};
    *(uint2*)(fused + (size_t)idx * 4) = *(const uint2*)o;
}

// RoPE on q -> (H, T, HD) bf16, with 1/sqrt(HD) folded in.
__global__ void rope_q_kernel(const short* __restrict__ q, short* __restrict__ qr)
{
    int idx = blockIdx.x * blockDim.x + threadIdx.x;   // T*NH*64
    int d = idx & 63;
    int h = (idx >> 6) & 15;
    int t = idx >> 10;
    float fr = (float)t * __expf(-(float)d * 0.14391156831212787f);
    float s, c;
    sincosf(fr, &s, &c);
    const float sc = 0.08838834764831845f;  // 1/sqrt(128)
    const short* src = q + (size_t)t * D_MODEL + h * HD;
    float x1 = bf16_to_f32(src[d]) * sc, x2 = bf16_to_f32(src[d + 64]) * sc;
    short* dst = qr + ((size_t)h * T_SEQ + t) * HD;
    dst[d]      = f32_to_bf16(x1 * c - x2 * s);
    dst[d + 64] = f32_to_bf16(x2 * c + x1 * s);
}

// RoPE on k-half of kv (bf16 T x 1024) -> (KVH, T, HD) bf16.
__global__ void rope_k_kernel(const short* __restrict__ kv, short* __restrict__ kr)
{
    int idx = blockIdx.x * blockDim.x + threadIdx.x;   // T*NKVH*64
    int d = idx & 63;
    int kh = (idx >> 6) & 3;
    int t = idx >> 8;
    float fr = (float)t * __expf(-(float)d * 0.14391156831212787f);
    float s, c;
    sincosf(fr, &s, &c);
    const short* src = kv + (size_t)t * 1024 + kh * HD;
    float x1 = bf16_to_f32(src[d]), x2 = bf16_to_f32(src[d + 64]);
    short* dst = kr + ((size_t)kh * T_SEQ + t) * HD;
    dst[d]      = f32_to_bf16(x1 * c - x2 * s);
    dst[d + 64] = f32_to_bf16(x2 * c + x1 * s);
}

// ---------------------------------------------------------------------------
// Causal flash attention (exact R4 version, measured 50 us): max-free
// softmax, paired q-tiles (17 KV-128 iters/block), KV-128 dbuf staging,
// vmcnt(0)+barrier, xor-swizzled chunks, wave-private P.
// ---------------------------------------------------------------------------
__global__ __launch_bounds__(256, 1) void attn_kernel(
    const short* __restrict__ Qr, const short* __restrict__ Kr,
    const short* __restrict__ Vt, short* __restrict__ Out)
{
    const int pi = blockIdx.x;          // 0..15
    const int h = blockIdx.y;
    const int kvh = h >> 2;
    const int tid = threadIdx.x;
    const int wave = tid >> 6, lane = tid & 63;
    const int l16 = lane & 15, quad = lane >> 4;

    __shared__ short Klds[2][128 * 128];   // 64 KB, swizzled chunks
    __shared__ short Vlds[2][128 * 128];   // 64 KB, [hd][kv] swizzled
    __shared__ short Plds[4][16][136];     // 17 KB, padded (+8)

    const short* kbase = Kr + (size_t)kvh * T_SEQ * HD;
    const short* vbase = Vt + (size_t)kvh * HD * T_SEQ;

    for (int ph = 0; ph < 2; ++ph) {
        const int qt = ph ? (31 - pi) : pi;
        const int qbase = qt * 64 + wave * 16;
        const int n = (qt * 64 + 191) >> 7;     // ceil((qt+1)*64 / 128)

        bf16x8 qf[4];
        {
            const short* qrow = Qr + ((size_t)h * T_SEQ + qbase + l16) * HD;
            #pragma unroll
            for (int kc = 0; kc < 4; ++kc)
                qf[kc] = *(const bf16x8*)&qrow[kc * 32 + quad * 8];
        }
        f32x4 o[8] = {};
        float lsum[4] = {0.0f, 0.0f, 0.0f, 0.0f};

        __syncthreads();   // previous phase fully done with LDS

        {
            const short* ks = kbase;
            #pragma unroll
            for (int p = 0; p < 8; ++p) {
                int li = p * 256 + tid;
                int row = li >> 4, gs = (li & 15) ^ (row & 15);
                gl_to_lds16(ks + (size_t)row * HD + gs * 8,
                            &Klds[0][(size_t)(p * 256 + wave * 64) * 8]);
            }
            #pragma unroll
            for (int p = 0; p < 8; ++p) {
                int li = p * 256 + tid;
                int row = li >> 4, gs = (li & 15) ^ (row & 15);
                gl_to_lds16(vbase + (size_t)row * T_SEQ + gs * 8,
                            &Vlds[0][(size_t)(p * 256 + wave * 64) * 8]);
            }
        }

        for (int t = 0; t < n; ++t) {
            asm volatile("s_waitcnt vmcnt(0)\n\ts_barrier" ::: "memory");

            if (t + 1 < n) {   // prefetch next tile; overlaps compute below
                int kv1 = (t + 1) << 7;
                int nb = (t + 1) & 1;
                const short* ks = kbase + (size_t)kv1 * HD;
                #pragma unroll
                for (int p = 0; p < 8; ++p) {
                    int li = p * 256 + tid;
                    int row = li >> 4, gs = (li & 15) ^ (row & 15);
                    gl_to_lds16(ks + (size_t)row * HD + gs * 8,
                                &Klds[nb][(size_t)(p * 256 + wave * 64) * 8]);
                }
                #pragma unroll
                for (int p = 0; p < 8; ++p) {
                    int li = p * 256 + tid;
                    int row = li >> 4, gs = (li & 15) ^ (row & 15);
                    gl_to_lds16(vbase + (size_t)row * T_SEQ + kv1 + gs * 8,
                                &Vlds[nb][(size_t)(p * 256 + wave * 64) * 8]);
                }
            }

            const short* Kb = Klds[t & 1];
            const short* Vb = Vlds[t & 1];

            f32x4 s[8];
            #pragma unroll
            for (int ni = 0; ni < 8; ++ni) s[ni] = (f32x4){0, 0, 0, 0};
            #pragma unroll
            for (int ni = 0; ni < 8; ++ni)
                #pragma unroll
                for (int kc = 0; kc < 4; ++kc) {
                    bf16x8 b = *(const bf16x8*)
                        &Kb[(size_t)(ni * 16 + l16) * 128 + (((kc * 4 + quad) ^ l16) * 8)];
                    s[ni] = __builtin_amdgcn_mfma_f32_16x16x32_bf16(qf[kc], b, s[ni], 0, 0, 0);
                }

            if (t == n - 1) {
                int kvg0 = t << 7;
                #pragma unroll
                for (int ni = 0; ni < 8; ++ni) {
                    int kvg = kvg0 + ni * 16 + l16;
                    #pragma unroll
                    for (int r = 0; r < 4; ++r) {
                        int qg = qbase + quad * 4 + r;
                        float p = (kvg <= qg) ? __expf(s[ni][r]) : 0.0f;
                        lsum[r] += p;
                        Plds[wave][quad * 4 + r][ni * 16 + l16] = f32_to_bf16(p);
                    }
                }
            } else {
                #pragma unroll
                for (int ni = 0; ni < 8; ++ni)
                    #pragma unroll
                    for (int r = 0; r < 4; ++r) {
                        float p = __expf(s[ni][r]);
                        lsum[r] += p;
                        Plds[wave][quad * 4 + r][ni * 16 + l16] = f32_to_bf16(p);
                    }
            }
            asm volatile("s_waitcnt lgkmcnt(0)" ::: "memory");

            #pragma unroll
            for (int d8 = 0; d8 < 8; ++d8)
                #pragma unroll
                for (int r = 0; r < 4; ++r) o[d8][r] *= 1.0f;   // no rescale (max-free)
            #pragma unroll
            for (int kc = 0; kc < 4; ++kc) {
                bf16x8 pa = *(const bf16x8*)&Plds[wave][l16][kc * 32 + quad * 8];
                #pragma unroll
                for (int d8 = 0; d8 < 8; ++d8) {
                    bf16x8 b = *(const bf16x8*)
                        &Vb[(size_t)(d8 * 16 + l16) * 128 + (((kc * 4 + quad) ^ l16) * 8)];
                    o[d8] = __builtin_amdgcn_mfma_f32_16x16x32_bf16(pa, b, o[d8], 0, 0, 0);
                }
            }
        }

        #pragma unroll
        for (int r = 0; r < 4; ++r) {
            #pragma unroll
            for (int off = 1; off < 16; off <<= 1)
                lsum[r] += __shfl_xor(lsum[r], off);
            lsum[r] = 1.0f / lsum[r];
        }
        #pragma unroll
        for (int d8 = 0; d8 < 8; ++d8)
            #pragma unroll
            for (int r = 0; r < 4; ++r) {
                int row = qbase + quad * 4 + r;
                Out[(size_t)row * D_MODEL + h * HD + d8 * 16 + l16] =
                    f32_to_bf16(o[d8][r] * lsum[r]);
            }
    }
}

// ---------------------------------------------------------------------------
extern "C" void kernel_launch(void* const* d_in, const int* in_sizes, int n_in,
                              void* d_out, int out_size, void* d_ws, size_t ws_size,
                              hipStream_t stream)
{
    const float* hs  = (const float*)d_in[0];
    const float* Wq  = (const float*)d_in[1];
    const float* Wk  = (const float*)d_in[2];
    const float* Wv  = (const float*)d_in[3];
    const float* Wo  = (const float*)d_in[4];
    const float* Wr1 = (const float*)d_in[5];
    const float* br1 = (const float*)d_in[6];
    const float* Wr2 = (const float*)d_in[7];
    const float* br2 = (const float*)d_in[8];
    float* out = (float*)d_out;

    char* w = (char*)d_ws;
    const size_t MB = 1u << 20;
    float* l2_f     = (float*)(w + 0 * MB);    // 16 MB
    short* hs_bf    = (short*)(w + 16 * MB);   // 8 MB (aliased as attn_bf later)
    short* Wq_t     = (short*)(w + 24 * MB);   // 8 MB
    short* Wkv_t    = (short*)(w + 32 * MB);   // 4 MB  [Wk^T | Wv^T]
    short* Wr1_t    = (short*)(w + 36 * MB);   // 4 MB
    short* Wo_t     = (short*)(w + 40 * MB);   // 8 MB
    short* q_bf     = (short*)(w + 48 * MB);   // 8 MB
    short* h_bf     = (short*)(w + 56 * MB);   // 4 MB
    short* fused_bf = (short*)(w + 60 * MB);   // 8 MB
    short* kv_bf    = (short*)(w + 68 * MB);   // 4 MB
    short* qr       = (short*)(w + 72 * MB);   // 8 MB (H,T,HD), roped+scaled
    short* kr       = (short*)(w + 80 * MB);   // 2 MB (KVH,T,HD), roped
    short* vr       = (short*)(w + 82 * MB);   // 2 MB (KVH,HD,T)
    float* lam_f    = (float*)(w + 84 * MB);   // 16 KB
    short* attn_bf  = hs_bf;                   // alias: hs_bf dead after q-gemm

    transpose_all_kernel<<<dim3(192, 64), 256, 0, stream>>>(
        Wq, Wk, Wv, Wr1, Wo, Wq_t, Wkv_t, Wr1_t, Wo_t);

    ema_kernel<<<dim3(T_SEQ / 128, D_MODEL / 256), 256, 0, stream>>>(hs, l2_f, hs_bf);

    // q = hs @ Wq : 16 x 32 = 512 blocks (2/CU)
    gemm_bt_kernel<128><<<dim3(16, 32), 256, 0, stream>>>(
        hs_bf, Wq_t, nullptr, q_bf, 2048, 2048, 2048, nullptr, 0);

    // h = silu(q @ Wr1 + br1) : BN=64 -> 16 x 32 = 512 blocks
    gemm_bt_kernel<64><<<dim3(16, 32), 256, 0, stream>>>(
        q_bf, Wr1_t, nullptr, h_bf, 2048, 1024, 2048, br1, 1);

    lam_kernel<<<T_SEQ, 64, 0, stream>>>(h_bf, Wr2, br2, lam_f);

    fuse_kernel<<<(T_SEQ * D_MODEL / 4) / 256, 256, 0, stream>>>(hs, l2_f, lam_f, fused_bf);

    // [k|v] = fused @ [Wk|Wv] : BN=64 -> 512 blocks
    gemm_bt_kernel<64><<<dim3(16, 32), 256, 0, stream>>>(
        fused_bf, Wkv_t, nullptr, kv_bf, 2048, 1024, 2048, nullptr, 0);

    rope_q_kernel<<<(T_SEQ * NH * 64) / 256, 256, 0, stream>>>(q_bf, qr);
    rope_k_kernel<<<(T_SEQ * NKVH * 64) / 256, 256, 0, stream>>>(kv_bf, kr);
    transpose_bf_kernel<<<dim3(16, 64), 256, 0, stream>>>(kv_bf + 512, 1024, vr, 2048);

    attn_kernel<<<dim3(16, NH), 256, 0, stream>>>(qr, kr, vr, attn_bf);

    // out = attn @ Wo : 512 blocks
    gemm_bt_kernel<128><<<dim3(16, 32), 256, 0, stream>>>(
        attn_bf, Wo_t, out, nullptr, 2048, 2048, 2048, nullptr, 0);
}